// Round 11
// baseline (590.472 us; speedup 1.0000x reference)
//
#include <hip/hip_runtime.h>

#define N_NODES 50000
#define E_EDGES 200000
#define ET_EDGES (E_EDGES + N_NODES)
#define G_GRAPHS 2000
#define F_IN 64
#define HID 128
#define HEADS 4
#define DM 512
#define BN_EPS 1e-5f
#define NEG_SLOPE 0.2f
#define YBLK 391            // (N_NODES+127)/128
#define NCHUNK (YBLK / 8)   // 48 full 8-row chunks
#define NBLK 49             // (N_NODES+1023)/1024 scan blocks
#define AGG_NPB 32          // nodes per aggregate block (8 waves x 4)

typedef unsigned short ushort_t;
typedef float floatx4 __attribute__((ext_vector_type(4)));
typedef short short8 __attribute__((ext_vector_type(8)));

__device__ __forceinline__ float b2f(unsigned int u) {
    union { unsigned int i; float f; } v; v.i = u << 16; return v.f;
}
__device__ __forceinline__ ushort_t f2b(float f) {
    union { float f; unsigned int i; } v; v.f = f;
    unsigned int r = v.i + 0x7FFFu + ((v.i >> 16) & 1u);   // RNE
    return (ushort_t)(r >> 16);
}
__device__ __forceinline__ void unpack8(uint4 v, float* f) {
    f[0] = b2f(v.x & 0xffffu); f[1] = b2f(v.x >> 16);
    f[2] = b2f(v.y & 0xffffu); f[3] = b2f(v.y >> 16);
    f[4] = b2f(v.z & 0xffffu); f[5] = b2f(v.z >> 16);
    f[6] = b2f(v.w & 0xffffu); f[7] = b2f(v.w >> 16);
}
// async global->LDS, 16B per lane; LDS dest is wave-uniform base + lane*16
__device__ __forceinline__ void glds16(const ushort_t* g, ushort_t* l) {
    __builtin_amdgcn_global_load_lds(
        (const __attribute__((address_space(1))) unsigned int*)g,
        (__attribute__((address_space(3))) unsigned int*)l, 16, 0, 0);
}

// ---------- combined prep: x->bf16 + 3x W[K,512]->Wt[512,K] bf16 ----------
#define XN (N_NODES * F_IN)
#define W0N (F_IN * DM)
#define W1N (DM * DM)
__global__ __launch_bounds__(256) void k_prep(const float* __restrict__ x,
                                              const float* __restrict__ w0,
                                              const float* __restrict__ w1,
                                              const float* __restrict__ w2,
                                              ushort_t* __restrict__ Xb,
                                              ushort_t* __restrict__ Wh0,
                                              ushort_t* __restrict__ Wh1,
                                              ushort_t* __restrict__ Wh2) {
    int t = blockIdx.x * 256 + threadIdx.x;
    if (t < XN) { Xb[t] = f2b(x[t]); return; }
    t -= XN;
    if (t < W0N) {
        int k = t >> 9, n = t & 511;
        Wh0[(size_t)n * F_IN + k] = f2b(w0[t]);
        return;
    }
    t -= W0N;
    if (t < W1N) {
        int k = t >> 9, n = t & 511;
        Wh1[(size_t)n * DM + k] = f2b(w1[t]);
        return;
    }
    t -= W1N;
    if (t < W1N) {
        int k = t >> 9, n = t & 511;
        Wh2[(size_t)n * DM + k] = f2b(w2[t]);
    }
}

// ---------- attention-score weight vectors: ws[h][v][k] = sum_c W[k,h*128+c]*a_v[h,c]
__global__ __launch_bounds__(256) void k_wsprep(const float* __restrict__ w0,
                                                const float* __restrict__ as0, const float* __restrict__ ad0,
                                                const float* __restrict__ w1,
                                                const float* __restrict__ as1, const float* __restrict__ ad1,
                                                const float* __restrict__ w2,
                                                const float* __restrict__ as2, const float* __restrict__ ad2,
                                                ushort_t* __restrict__ ws0,
                                                ushort_t* __restrict__ ws1,
                                                ushort_t* __restrict__ ws2) {
    int b = blockIdx.x;                 // 24 blocks: (layer, head, v)
    int l = b >> 3, h = (b >> 1) & 3, v = b & 1;
    const float* w = l == 0 ? w0 : l == 1 ? w1 : w2;
    const float* a = v == 0 ? (l == 0 ? as0 : l == 1 ? as1 : as2)
                            : (l == 0 ? ad0 : l == 1 ? ad1 : ad2);
    ushort_t* o = l == 0 ? ws0 : l == 1 ? ws1 : ws2;
    int K = l == 0 ? F_IN : DM;
    __shared__ float av[HID];
    int t = threadIdx.x;
    if (t < HID) av[t] = a[h * HID + t];
    __syncthreads();
    for (int k = t; k < K; k += 256) {
        const float* wr = w + (size_t)k * DM + h * HID;
        float s = 0.f;
#pragma unroll 8
        for (int c = 0; c < HID; ++c) s += wr[c] * av[c];
        o[(h * 2 + v) * K + k] = f2b(s);
    }
}

// ---------- MFMA GEMM: 3-stage glds pipeline, counted vmcnt (T4) + setprio (T5) --
// C[M,512](bf16) = A[M,K] @ W; scores ssrc/sdst = A @ ws (2 extra cols via MFMA).
// T5: counted-vmcnt creates wave role-split (STAGE-issuing vs MFMA-entering);
// setprio(1) around the MFMA cluster lets the CU scheduler favor matrix waves.
__global__ __launch_bounds__(256) void k_mgemm(const ushort_t* __restrict__ A,
                                               const ushort_t* __restrict__ Bh,
                                               const ushort_t* __restrict__ ws,
                                               ushort_t* __restrict__ C,
                                               float* __restrict__ ssrc,
                                               float* __restrict__ sdst,
                                               int M, int K) {
    __shared__ __align__(16) ushort_t Ash[3][128 * 32];
    __shared__ __align__(16) ushort_t Bsh[3][128 * 32];
    __shared__ __align__(16) ushort_t wsh[2 * 512];
    // ---- XCD-grouping block index map ----
    int bid = blockIdx.x;
    int head, yb;
    if (bid < NCHUNK * 32) {
        int chunk = bid >> 5, pos = bid & 31;
        yb = chunk * 8 + (pos & 7);
        head = pos >> 3;
    } else {
        int rem = bid - NCHUNK * 32;
        head = rem & 3;
        yb = NCHUNK * 8 + (rem >> 2);
    }
    int m0 = yb * 128, n0 = head * 128;
    int tid = threadIdx.x;
    int lane = tid & 63, wave = tid >> 6;
    int wm = (wave >> 1) * 64, wn = (wave & 1) * 64;
    floatx4 acc[4][4] = {};
    floatx4 sacc[4] = {};                             // score accum: col0=ps, col1=pd
    for (int i = tid; i < 2 * K; i += 256)
        wsh[i] = ws[(size_t)head * 2 * K + i];
    // ---- staging geometry: wave w fills rows [w*16,w*16+16) and +64, 1KB/issue
    int lrow = lane >> 2, lchunk = lane & 3;          // row-within-16, 16B chunk
    int fs = (lrow & 3) ^ ((lrow >> 2) & 3);          // same f(row) the reads use
    int schunk = lchunk ^ fs;                         // pre-swizzled global chunk
    int ar0 = wave * 16 + lrow;
    int ar1 = ar0 + 64;
    int gr0 = m0 + ar0; if (gr0 >= M) gr0 = M - 1;
    int gr1 = m0 + ar1; if (gr1 >= M) gr1 = M - 1;
    const ushort_t* gA0 = A + (size_t)gr0 * K + schunk * 8;
    const ushort_t* gA1 = A + (size_t)gr1 * K + schunk * 8;
    const ushort_t* gB0 = Bh + (size_t)(n0 + ar0) * K + schunk * 8;
    const ushort_t* gB1 = Bh + (size_t)(n0 + ar1) * K + schunk * 8;
    int rF = lane & 15, q = lane >> 4;
    int swz = ((q ^ (rF & 3) ^ ((rF >> 2) & 3))) * 8; // read-side chunk pos
    ushort_t* As0 = &Ash[0][0]; ushort_t* As1 = &Ash[1][0]; ushort_t* As2 = &Ash[2][0];
    ushort_t* Bs0 = &Bsh[0][0]; ushort_t* Bs1 = &Bsh[1][0]; ushort_t* Bs2 = &Bsh[2][0];
    auto STAGE = [&](ushort_t* Ab, ushort_t* Bb, int koff) {
        glds16(gA0 + koff, Ab + (wave * 16) * 32);
        glds16(gA1 + koff, Ab + (wave * 16 + 64) * 32);
        glds16(gB0 + koff, Bb + (wave * 16) * 32);
        glds16(gB1 + koff, Bb + (wave * 16 + 64) * 32);
    };
    __syncthreads();                      // wsh visible; drains ws loads (vmcnt=0 here)
    STAGE(As0, Bs0, 0);                   // prologue: 2 tiles in flight
    if (K > 32) STAGE(As1, Bs1, 32);
    for (int k0 = 0; k0 < K; k0 += 32) {
        if (k0 + 32 < K) asm volatile("s_waitcnt vmcnt(4)" ::: "memory");
        else             asm volatile("s_waitcnt vmcnt(0)" ::: "memory");
        __builtin_amdgcn_s_barrier();     // all waves' STAGE(t) complete
        __builtin_amdgcn_sched_barrier(0);// pin ds_reads/STAGE below the barrier
        if (k0 + 64 < K) STAGE(As2, Bs2, k0 + 64);   // dist-2 prefetch
        short8 sf = *(const short8*)&wsh[(rF & 1) * K + q * 8 + k0];
        short8 af[4], bf[4];
#pragma unroll
        for (int i = 0; i < 4; ++i)
            af[i] = *(const short8*)&As0[(wm + i * 16 + rF) * 32 + swz];
#pragma unroll
        for (int j = 0; j < 4; ++j)
            bf[j] = *(const short8*)&Bs0[(wn + j * 16 + rF) * 32 + swz];
        __builtin_amdgcn_s_setprio(1);    // T5: favor MFMA-entering waves
#pragma unroll
        for (int i = 0; i < 4; ++i) {
            sacc[i] = __builtin_amdgcn_mfma_f32_16x16x32_bf16(af[i], sf, sacc[i], 0, 0, 0);
#pragma unroll
            for (int j = 0; j < 4; ++j)
                acc[i][j] = __builtin_amdgcn_mfma_f32_16x16x32_bf16(af[i], bf[j], acc[i][j], 0, 0, 0);
        }
        __builtin_amdgcn_s_setprio(0);
        ushort_t* tA = As0; As0 = As1; As1 = As2; As2 = tA;
        ushort_t* tB = Bs0; Bs0 = Bs1; Bs1 = Bs2; Bs2 = tB;
    }
    // C/D layout: col=lane&15, row=(lane>>4)*4+reg   [m89-verified]
    int cr = (lane >> 4) * 4, cc = lane & 15;
#pragma unroll
    for (int i = 0; i < 4; ++i) {
#pragma unroll
        for (int r = 0; r < 4; ++r) {
            int gr = m0 + wm + i * 16 + cr + r;
            if (gr < M) {
#pragma unroll
                for (int j = 0; j < 4; ++j)
                    C[(size_t)gr * DM + n0 + wn + j * 16 + cc] = f2b(acc[i][j][r]);
                if (cc == 0) ssrc[gr * 4 + head] = sacc[i][r];
                else if (cc == 1) sdst[gr * 4 + head] = sacc[i][r];
            }
        }
    }
}

// ---------- BN apply + ReLU, elementwise bf16->bf16 ----------
__global__ __launch_bounds__(256) void k_bnapply(const ushort_t* __restrict__ X,
                                                 const float* __restrict__ stat,
                                                 const float* __restrict__ gam,
                                                 const float* __restrict__ bet,
                                                 ushort_t* __restrict__ Y) {
    __shared__ float sc[512], sh[512];
    int t = threadIdx.x;
    for (int f = t; f < 512; f += 256) {
        float mu = stat[f] * (1.f / (float)N_NODES);
        float var = fmaxf(stat[512 + f] * (1.f / (float)N_NODES) - mu * mu, 0.f);
        float rs = rsqrtf(var + BN_EPS);
        float s = gam[f] * rs;
        sc[f] = s;
        sh[f] = bet[f] - mu * s;
    }
    __syncthreads();
    int c8 = (t & 63) * 8;                       // 8 features per thread
    const float* scp = sc + c8;
    const float* shp = sh + c8;
    for (int n = blockIdx.x * 4 + (t >> 6); n < N_NODES; n += gridDim.x * 4) {
        uint4 v = *(const uint4*)&X[(size_t)n * DM + c8];
        float fv[8]; unpack8(v, fv);
        uint4 ov; unsigned* po = (unsigned*)&ov;
#pragma unroll
        for (int j = 0; j < 4; ++j) {
            unsigned lo = f2b(fmaxf(fv[2 * j] * scp[2 * j] + shp[2 * j], 0.f));
            unsigned hi = f2b(fmaxf(fv[2 * j + 1] * scp[2 * j + 1] + shp[2 * j + 1], 0.f));
            po[j] = lo | (hi << 16);
        }
        *(uint4*)&Y[(size_t)n * DM + c8] = ov;
    }
}

// ---------- CSR build ----------
__global__ void k_degree(const int* __restrict__ ei, int* __restrict__ deg) {
    int e = blockIdx.x * blockDim.x + threadIdx.x;
    if (e >= ET_EDGES) return;
    int d = (e < E_EDGES) ? ei[E_EDGES + e] : (e - E_EDGES);
    atomicAdd(&deg[d], 1);
}

// ---------- 3-phase parallel exclusive scan ----------
__global__ __launch_bounds__(1024) void k_scanA(const int* __restrict__ deg,
                                                int* __restrict__ bsum) {
    __shared__ int wsum[16];
    int t = threadIdx.x, lane = t & 63, wv = t >> 6;
    int i = blockIdx.x * 1024 + t;
    int v = (i < N_NODES) ? deg[i] : 0;
#pragma unroll
    for (int off = 32; off > 0; off >>= 1) v += __shfl_down(v, off);
    if (lane == 0) wsum[wv] = v;
    __syncthreads();
    if (t == 0) {
        int s = 0;
#pragma unroll
        for (int w = 0; w < 16; ++w) s += wsum[w];
        bsum[blockIdx.x] = s;
    }
}

__global__ __launch_bounds__(64) void k_scanB(const int* __restrict__ bsum,
                                              int* __restrict__ bpre,
                                              int* __restrict__ offs) {
    int l = threadIdx.x;
    int v = (l < NBLK) ? bsum[l] : 0;
    int x = v;
#pragma unroll
    for (int off = 1; off < 64; off <<= 1) {
        int y = __shfl_up(x, off);
        if (l >= off) x += y;
    }
    if (l < NBLK) bpre[l] = x - v;       // exclusive block prefix
    if (l == NBLK - 1) offs[N_NODES] = x;
}

__global__ __launch_bounds__(1024) void k_scanC(const int* __restrict__ deg,
                                                const int* __restrict__ bpre,
                                                int* __restrict__ offs,
                                                int* __restrict__ cursor) {
    __shared__ int wsum[16];
    int t = threadIdx.x, lane = t & 63, wv = t >> 6;
    int i = blockIdx.x * 1024 + t;
    int v = (i < N_NODES) ? deg[i] : 0;
    int x = v;
#pragma unroll
    for (int off = 1; off < 64; off <<= 1) {
        int y = __shfl_up(x, off);
        if (lane >= off) x += y;
    }
    if (lane == 63) wsum[wv] = x;
    __syncthreads();
    int wpre = 0;
#pragma unroll
    for (int w = 0; w < 16; ++w) wpre += (w < wv) ? wsum[w] : 0;
    int incl = wpre + x;
    if (i < N_NODES) {
        int o = bpre[blockIdx.x] + incl - v;
        offs[i] = o; cursor[i] = o;
    }
}

__global__ void k_scatter(const int* __restrict__ ei, int* __restrict__ cursor,
                          int* __restrict__ csr_src) {
    int e = blockIdx.x * blockDim.x + threadIdx.x;
    if (e >= ET_EDGES) return;
    int sv, d;
    if (e < E_EDGES) { sv = ei[e]; d = ei[E_EDGES + e]; } else { sv = d = e - E_EDGES; }
    int pos = atomicAdd(&cursor[d], 1);
    csr_src[pos] = sv;
}

__global__ void k_gbounds(const int* __restrict__ batch, int* __restrict__ gstart) {
    int i = blockIdx.x * blockDim.x + threadIdx.x;
    if (i >= N_NODES) return;
    int b = batch[i];
    int p = (i == 0) ? -1 : batch[i - 1];
    for (int g = p + 1; g <= b; ++g) gstart[g] = i;
    if (i == N_NODES - 1)
        for (int g = b + 1; g <= G_GRAPHS; ++g) gstart[g] = N_NODES;
}

// ---------- GAT softmax + aggregate + fused BN stats (r10, unchanged) ----------
__global__ __launch_bounds__(512) void k_aggstats(const ushort_t* __restrict__ H,
                                                  const float* __restrict__ ssrc,
                                                  const float* __restrict__ sdst,
                                                  const int* __restrict__ offs,
                                                  const int* __restrict__ csr_src,
                                                  const float* __restrict__ bias,
                                                  ushort_t* __restrict__ out,
                                                  float* __restrict__ stat) {
    __shared__ float sS[8][512], sQ[8][512];
    int tid = threadIdx.x;
    int wave = tid >> 6, lane = tid & 63;
    int hl = lane >> 4, li = lane & 15;       // head group, index within group
    int gbase = hl << 4;                       // first lane of this head group
    const float* bp = bias + lane * 8;
    float4 b0 = *(const float4*)bp;
    float4 b1 = *(const float4*)(bp + 4);
    float sa[8] = { 0.f }, qa[8] = { 0.f };
    int nbase = blockIdx.x * AGG_NPB + wave * 4;
    for (int ni = 0; ni < 4; ++ni) {
        int n = nbase + ni;
        if (n < N_NODES) {
            int beg = offs[n], end = offs[n + 1];
            int deg = end - beg;
            float sdh = sdst[n * 4 + hl];
            float acc[8] = { 0.f, 0.f, 0.f, 0.f, 0.f, 0.f, 0.f, 0.f };
            if (deg <= 16) {
                // ---- pass 1: one edge per group lane, tree softmax ----
                int sv_li = csr_src[beg + (li < deg ? li : 0)];
                float sc = -1e30f;
                if (li < deg) {
                    float t = ssrc[sv_li * 4 + hl] + sdh;
                    sc = t > 0.f ? t : NEG_SLOPE * t;
                }
                float m = sc;
#pragma unroll
                for (int mk = 1; mk < 16; mk <<= 1) m = fmaxf(m, __shfl_xor(m, mk));
                float ex = (li < deg) ? __expf(sc - m) : 0.f;
                float s = ex;
#pragma unroll
                for (int mk = 1; mk < 16; mk <<= 1) s += __shfl_xor(s, mk);
                float alf = ex / s;            // lane li holds alpha of edge li
                // ---- pass 2: 4-edge pipelined gather, alpha/src via shfl ----
                int e = beg;
                for (; e + 4 <= end; e += 4) {
                    int i0 = e - beg;
                    int sv0 = __shfl(sv_li, gbase + i0);
                    int sv1 = __shfl(sv_li, gbase + i0 + 1);
                    int sv2 = __shfl(sv_li, gbase + i0 + 2);
                    int sv3 = __shfl(sv_li, gbase + i0 + 3);
                    uint4 h0 = *(const uint4*)&H[(size_t)sv0 * DM + lane * 8];
                    uint4 h1 = *(const uint4*)&H[(size_t)sv1 * DM + lane * 8];
                    uint4 h2 = *(const uint4*)&H[(size_t)sv2 * DM + lane * 8];
                    uint4 h3 = *(const uint4*)&H[(size_t)sv3 * DM + lane * 8];
                    float a0 = __shfl(alf, gbase + i0);
                    float a1 = __shfl(alf, gbase + i0 + 1);
                    float a2 = __shfl(alf, gbase + i0 + 2);
                    float a3 = __shfl(alf, gbase + i0 + 3);
                    float f0[8], f1[8], f2[8], f3[8];
                    unpack8(h0, f0); unpack8(h1, f1); unpack8(h2, f2); unpack8(h3, f3);
#pragma unroll
                    for (int j = 0; j < 8; ++j)
                        acc[j] += a0 * f0[j] + a1 * f1[j] + a2 * f2[j] + a3 * f3[j];
                }
                for (; e < end; ++e) {
                    int idx = e - beg;
                    int sv = __shfl(sv_li, gbase + idx);
                    float al = __shfl(alf, gbase + idx);
                    uint4 hv = *(const uint4*)&H[(size_t)sv * DM + lane * 8];
                    float f[8]; unpack8(hv, f);
#pragma unroll
                    for (int j = 0; j < 8; ++j) acc[j] += al * f[j];
                }
            } else {
                // ---- rare deg>16 fallback: online softmax + 4-edge gather ----
                float m = -1e30f, s = 0.f;
                for (int e = beg + li; e < end; e += 16) {
                    float sc = ssrc[csr_src[e] * 4 + hl] + sdh;
                    sc = sc > 0.f ? sc : NEG_SLOPE * sc;
                    if (sc > m) { s = s * __expf(m - sc) + 1.f; m = sc; }
                    else s += __expf(sc - m);
                }
#pragma unroll
                for (int mk = 1; mk < 16; mk <<= 1) {
                    float om = __shfl_xor(m, mk), os = __shfl_xor(s, mk);
                    float mn = fmaxf(m, om);
                    s = s * __expf(m - mn) + os * __expf(om - mn);
                    m = mn;
                }
                float mh = m, inv = 1.f / s;
                int e = beg;
                for (; e + 4 <= end; e += 4) {
                    int sv0 = csr_src[e], sv1 = csr_src[e + 1];
                    int sv2 = csr_src[e + 2], sv3 = csr_src[e + 3];
                    float s0 = ssrc[sv0 * 4 + hl], s1 = ssrc[sv1 * 4 + hl];
                    float s2 = ssrc[sv2 * 4 + hl], s3 = ssrc[sv3 * 4 + hl];
                    uint4 h0 = *(const uint4*)&H[(size_t)sv0 * DM + lane * 8];
                    uint4 h1 = *(const uint4*)&H[(size_t)sv1 * DM + lane * 8];
                    uint4 h2 = *(const uint4*)&H[(size_t)sv2 * DM + lane * 8];
                    uint4 h3 = *(const uint4*)&H[(size_t)sv3 * DM + lane * 8];
                    s0 += sdh; s0 = s0 > 0.f ? s0 : NEG_SLOPE * s0;
                    s1 += sdh; s1 = s1 > 0.f ? s1 : NEG_SLOPE * s1;
                    s2 += sdh; s2 = s2 > 0.f ? s2 : NEG_SLOPE * s2;
                    s3 += sdh; s3 = s3 > 0.f ? s3 : NEG_SLOPE * s3;
                    float a0 = __expf(s0 - mh) * inv, a1 = __expf(s1 - mh) * inv;
                    float a2 = __expf(s2 - mh) * inv, a3 = __expf(s3 - mh) * inv;
                    float f0[8], f1[8], f2[8], f3[8];
                    unpack8(h0, f0); unpack8(h1, f1); unpack8(h2, f2); unpack8(h3, f3);
#pragma unroll
                    for (int j = 0; j < 8; ++j)
                        acc[j] += a0 * f0[j] + a1 * f1[j] + a2 * f2[j] + a3 * f3[j];
                }
                for (; e < end; ++e) {
                    int sv = csr_src[e];
                    float sc = ssrc[sv * 4 + hl] + sdh;
                    sc = sc > 0.f ? sc : NEG_SLOPE * sc;
                    float alpha = __expf(sc - mh) * inv;
                    uint4 hv = *(const uint4*)&H[(size_t)sv * DM + lane * 8];
                    float f[8]; unpack8(hv, f);
#pragma unroll
                    for (int j = 0; j < 8; ++j) acc[j] += alpha * f[j];
                }
            }
            acc[0] += b0.x; acc[1] += b0.y; acc[2] += b0.z; acc[3] += b0.w;
            acc[4] += b1.x; acc[5] += b1.y; acc[6] += b1.z; acc[7] += b1.w;
            uint4 ov; unsigned* po = (unsigned*)&ov;
#pragma unroll
            for (int j = 0; j < 4; ++j)
                po[j] = (unsigned)f2b(acc[2 * j]) | ((unsigned)f2b(acc[2 * j + 1]) << 16);
            *(uint4*)&out[(size_t)n * DM + lane * 8] = ov;
#pragma unroll
            for (int j = 0; j < 8; ++j) {       // BN stats (f32, pre-rounding)
                sa[j] += acc[j];
                qa[j] += acc[j] * acc[j];
            }
        }
    }
#pragma unroll
    for (int j = 0; j < 8; ++j) {
        sS[wave][lane * 8 + j] = sa[j];
        sQ[wave][lane * 8 + j] = qa[j];
    }
    __syncthreads();
    {
        int f = tid & 511;
        if (tid < 512) {
            float a = 0.f, b = 0.f;
#pragma unroll
            for (int w = 0; w < 8; ++w) { a += sS[w][f]; b += sQ[w][f]; }
            atomicAdd(&stat[f], a);
            atomicAdd(&stat[512 + f], b);
        }
    }
}

// ---------- fused graph pooling (BN+ReLU) + MLP head: one block per graph ----
__global__ __launch_bounds__(256) void k_poolmlp(const ushort_t* __restrict__ X,
                                                 const int* __restrict__ gstart,
                                                 const float* __restrict__ stat,
                                                 const float* __restrict__ gam,
                                                 const float* __restrict__ bet,
                                                 const float* __restrict__ c1w,
                                                 const float* __restrict__ c1b,
                                                 const float* __restrict__ c2w,
                                                 const float* __restrict__ c2b,
                                                 const float* __restrict__ c3w,
                                                 const float* __restrict__ c3b,
                                                 float* __restrict__ out) {
    __shared__ float row[1024];    // [0,512)=mean, [512,1024)=max
    __shared__ float part[128];
    __shared__ float h1[128];
    __shared__ float h2[64];
    int g = blockIdx.x, t = threadIdx.x;
    int beg = gstart[g], end = gstart[g + 1];
    // ---- pool phase: 2 feats/thread, BN+ReLU on the fly ----
    int f0 = t * 2;
    float mu0 = stat[f0] * (1.f / (float)N_NODES);
    float va0 = fmaxf(stat[512 + f0] * (1.f / (float)N_NODES) - mu0 * mu0, 0.f);
    float sc0 = gam[f0] * rsqrtf(va0 + BN_EPS);
    float sh0 = bet[f0] - mu0 * sc0;
    float mu1 = stat[f0 + 1] * (1.f / (float)N_NODES);
    float va1 = fmaxf(stat[512 + f0 + 1] * (1.f / (float)N_NODES) - mu1 * mu1, 0.f);
    float sc1 = gam[f0 + 1] * rsqrtf(va1 + BN_EPS);
    float sh1 = bet[f0 + 1] - mu1 * sc1;
    float s0 = 0.f, s1 = 0.f, m0 = -1e30f, m1 = -1e30f;
    for (int nn = beg; nn < end; ++nn) {
        unsigned v = *(const unsigned*)&X[(size_t)nn * DM + f0];
        float x0 = fmaxf(b2f(v & 0xffffu) * sc0 + sh0, 0.f);
        float x1 = fmaxf(b2f(v >> 16) * sc1 + sh1, 0.f);
        s0 += x0; s1 += x1;
        m0 = fmaxf(m0, x0); m1 = fmaxf(m1, x1);
    }
    float cnt = (float)(end - beg);
    float inv = cnt > 0.f ? 1.f / cnt : 0.f;
    row[f0] = s0 * inv;             row[f0 + 1] = s1 * inv;
    row[512 + f0] = cnt > 0.f ? m0 : 0.f;
    row[512 + f0 + 1] = cnt > 0.f ? m1 : 0.f;
    __syncthreads();
    // ---- MLP phase: 2-way K-split over the 1024-wide layer ----
    int half = t >> 7, c = t & 127;
    int k0 = half * 512;
    float a1 = 0.f;
#pragma unroll 8
    for (int k = 0; k < 512; ++k) a1 += row[k0 + k] * c1w[(k0 + k) * 128 + c];
    if (half) part[c] = a1;
    __syncthreads();
    if (!half) h1[c] = fmaxf(a1 + part[c] + c1b[c], 0.f);
    __syncthreads();
    if (t < 64) {
        float a2 = c2b[t];
#pragma unroll 8
        for (int k = 0; k < 128; ++k) a2 += h1[k] * c2w[k * 64 + t];
        h2[t] = fmaxf(a2, 0.f);
    }
    __syncthreads();
    if (t < 64) {
        float p = h2[t] * c3w[t];
#pragma unroll
        for (int off = 32; off > 0; off >>= 1) p += __shfl_down(p, off);
        if (t == 0) {
            float z = p + c3b[0];
            out[g] = 1.f / (1.f + __expf(-z));      // float32 output
        }
    }
}

extern "C" void kernel_launch(void* const* d_in, const int* in_sizes, int n_in,
                              void* d_out, int out_size, void* d_ws, size_t ws_size,
                              hipStream_t stream) {
    const float* x = (const float*)d_in[0];
    const int* ei = (const int*)d_in[1];
    const int* batch = (const int*)d_in[2];
    const float* c1w = (const float*)d_in[21];
    const float* c1b = (const float*)d_in[22];
    const float* c2w = (const float*)d_in[23];
    const float* c2b = (const float*)d_in[24];
    const float* c3w = (const float*)d_in[25];
    const float* c3b = (const float*)d_in[26];

    char* p = (char*)d_ws;
    auto carve = [&](size_t bytes) -> char* {
        char* r = p; p += (bytes + 255) & ~(size_t)255; return r;
    };
    ushort_t* buf0   = (ushort_t*)carve((size_t)N_NODES * DM * 2);   // ping-pong activations
    ushort_t* buf1   = (ushort_t*)carve((size_t)N_NODES * DM * 2);   // ping-pong activations
    ushort_t* Xb     = (ushort_t*)carve((size_t)N_NODES * F_IN * 2); // x in bf16
    ushort_t* Wh0    = (ushort_t*)carve((size_t)F_IN * DM * 2);      // W0^T (bf16)
    ushort_t* Wh1    = (ushort_t*)carve((size_t)DM * DM * 2);        // W1^T (bf16)
    ushort_t* Wh2    = (ushort_t*)carve((size_t)DM * DM * 2);        // W2^T (bf16)
    ushort_t* ws0    = (ushort_t*)carve((size_t)8 * F_IN * 2);       // W0@a vectors (bf16)
    ushort_t* ws1    = (ushort_t*)carve((size_t)8 * DM * 2);
    ushort_t* ws2    = (ushort_t*)carve((size_t)8 * DM * 2);
    float*    ssrc   = (float*)carve((size_t)N_NODES * 4 * 4);
    float*    sdst   = (float*)carve((size_t)N_NODES * 4 * 4);
    int*      deg    = (int*)carve((size_t)N_NODES * 4);
    int*      offs   = (int*)carve((size_t)(N_NODES + 1) * 4);
    int*      cursor = (int*)carve((size_t)N_NODES * 4);
    int*      csrsrc = (int*)carve((size_t)ET_EDGES * 4);
    float*    bnstat = (float*)carve(3 * 1024 * 4);                  // 3 layers' stats
    int*      gstart = (int*)carve((size_t)(G_GRAPHS + 1) * 4);
    int*      bsum   = (int*)carve(64 * 4);
    int*      bpre   = (int*)carve(64 * 4);

    // --- CSR by dst (self-loops appended) + graph bounds + all dtype prep ---
    hipMemsetAsync(deg, 0, (size_t)N_NODES * 4, stream);
    hipMemsetAsync(bnstat, 0, 3 * 1024 * 4, stream);
    k_degree<<<(ET_EDGES + 255) / 256, 256, 0, stream>>>(ei, deg);
    k_scanA<<<NBLK, 1024, 0, stream>>>(deg, bsum);
    k_scanB<<<1, 64, 0, stream>>>(bsum, bpre, offs);
    k_scanC<<<NBLK, 1024, 0, stream>>>(deg, bpre, offs, cursor);
    k_scatter<<<(ET_EDGES + 255) / 256, 256, 0, stream>>>(ei, cursor, csrsrc);
    k_gbounds<<<(N_NODES + 255) / 256, 256, 0, stream>>>(batch, gstart);
    {
        int total = XN + W0N + 2 * W1N;
        k_prep<<<(total + 255) / 256, 256, 0, stream>>>(
            x, (const float*)d_in[3], (const float*)d_in[9], (const float*)d_in[15],
            Xb, Wh0, Wh1, Wh2);
    }
    k_wsprep<<<24, 256, 0, stream>>>(
        (const float*)d_in[3], (const float*)d_in[4], (const float*)d_in[5],
        (const float*)d_in[9], (const float*)d_in[10], (const float*)d_in[11],
        (const float*)d_in[15], (const float*)d_in[16], (const float*)d_in[17],
        ws0, ws1, ws2);

    // Buffer schedule (ping-pong, no extra workspace):
    //  l0: in=Xb,   h=buf1, agg=buf0, An0->buf1
    //  l1: in=buf1, h=buf0, agg=buf1, An1->buf0
    //  l2: in=buf0, h=buf1, agg=buf0; poolmlp reads buf0 (pre-BN) + stat2
    const ushort_t* Whs[3] = { Wh0, Wh1, Wh2 };
    const ushort_t* wss[3] = { ws0, ws1, ws2 };
    const float* pgam = nullptr;
    const float* pbet = nullptr;
    const ushort_t* in = Xb;
    for (int l = 0; l < 3; ++l) {
        int K = (l == 0) ? F_IN : DM;
        const float* bia = (const float*)d_in[6 + 6 * l];
        const float* gam = (const float*)d_in[7 + 6 * l];
        const float* bet = (const float*)d_in[8 + 6 * l];
        ushort_t* h   = (l % 2 == 0) ? buf1 : buf0;
        ushort_t* agg = (l % 2 == 0) ? buf0 : buf1;

        k_mgemm<<<4 * YBLK, 256, 0, stream>>>(
            in, Whs[l], wss[l], h, ssrc, sdst, N_NODES, K);
        k_aggstats<<<(N_NODES + AGG_NPB - 1) / AGG_NPB, 512, 0, stream>>>(
            h, ssrc, sdst, offs, csrsrc, bia, agg, bnstat + l * 1024);
        if (l < 2)   // normalized input for next layer's GEMM, over dead h-buffer
            k_bnapply<<<2048, 256, 0, stream>>>(agg, bnstat + l * 1024, gam, bet, h);
        in = h;
        pgam = gam; pbet = bet;
    }
    k_poolmlp<<<G_GRAPHS, 256, 0, stream>>>(buf0, gstart, bnstat + 2 * 1024,
                                            pgam, pbet,
                                            c1w, c1b, c2w, c2b, c3w, c3b,
                                            (float*)d_out);
}

// Round 13
// 584.082 us; speedup vs baseline: 1.0109x; 1.0109x over previous
//
#include <hip/hip_runtime.h>

#define N_NODES 50000
#define E_EDGES 200000
#define ET_EDGES (E_EDGES + N_NODES)
#define G_GRAPHS 2000
#define F_IN 64
#define HID 128
#define HEADS 4
#define DM 512
#define BN_EPS 1e-5f
#define NEG_SLOPE 0.2f
#define YBLK 391            // (N_NODES+127)/128
#define NCHUNK (YBLK / 8)   // 48 full 8-row chunks
#define NBLK 49             // (N_NODES+1023)/1024 scan blocks
#define AGG_NPB 32          // nodes per aggregate block (8 waves x 4)

typedef unsigned short ushort_t;
typedef float floatx4 __attribute__((ext_vector_type(4)));
typedef short short8 __attribute__((ext_vector_type(8)));

__device__ __forceinline__ float b2f(unsigned int u) {
    union { unsigned int i; float f; } v; v.i = u << 16; return v.f;
}
__device__ __forceinline__ ushort_t f2b(float f) {
    union { float f; unsigned int i; } v; v.f = f;
    unsigned int r = v.i + 0x7FFFu + ((v.i >> 16) & 1u);   // RNE
    return (ushort_t)(r >> 16);
}
__device__ __forceinline__ void unpack8(uint4 v, float* f) {
    f[0] = b2f(v.x & 0xffffu); f[1] = b2f(v.x >> 16);
    f[2] = b2f(v.y & 0xffffu); f[3] = b2f(v.y >> 16);
    f[4] = b2f(v.z & 0xffffu); f[5] = b2f(v.z >> 16);
    f[6] = b2f(v.w & 0xffffu); f[7] = b2f(v.w >> 16);
}
// async global->LDS, 16B per lane; LDS dest is wave-uniform base + lane*16
__device__ __forceinline__ void glds16(const ushort_t* g, ushort_t* l) {
    __builtin_amdgcn_global_load_lds(
        (const __attribute__((address_space(1))) unsigned int*)g,
        (__attribute__((address_space(3))) unsigned int*)l, 16, 0, 0);
}

// ---------- combined prep: x->bf16 + 3x W[K,512]->Wt[512,K] bf16 ----------
#define XN (N_NODES * F_IN)
#define W0N (F_IN * DM)
#define W1N (DM * DM)
__global__ __launch_bounds__(256) void k_prep(const float* __restrict__ x,
                                              const float* __restrict__ w0,
                                              const float* __restrict__ w1,
                                              const float* __restrict__ w2,
                                              ushort_t* __restrict__ Xb,
                                              ushort_t* __restrict__ Wh0,
                                              ushort_t* __restrict__ Wh1,
                                              ushort_t* __restrict__ Wh2) {
    int t = blockIdx.x * 256 + threadIdx.x;
    if (t < XN) { Xb[t] = f2b(x[t]); return; }
    t -= XN;
    if (t < W0N) {
        int k = t >> 9, n = t & 511;
        Wh0[(size_t)n * F_IN + k] = f2b(w0[t]);
        return;
    }
    t -= W0N;
    if (t < W1N) {
        int k = t >> 9, n = t & 511;
        Wh1[(size_t)n * DM + k] = f2b(w1[t]);
        return;
    }
    t -= W1N;
    if (t < W1N) {
        int k = t >> 9, n = t & 511;
        Wh2[(size_t)n * DM + k] = f2b(w2[t]);
    }
}

// ---------- attention-score weight vectors: ws[h][v][k] = sum_c W[k,h*128+c]*a_v[h,c]
__global__ __launch_bounds__(256) void k_wsprep(const float* __restrict__ w0,
                                                const float* __restrict__ as0, const float* __restrict__ ad0,
                                                const float* __restrict__ w1,
                                                const float* __restrict__ as1, const float* __restrict__ ad1,
                                                const float* __restrict__ w2,
                                                const float* __restrict__ as2, const float* __restrict__ ad2,
                                                ushort_t* __restrict__ ws0,
                                                ushort_t* __restrict__ ws1,
                                                ushort_t* __restrict__ ws2) {
    int b = blockIdx.x;                 // 24 blocks: (layer, head, v)
    int l = b >> 3, h = (b >> 1) & 3, v = b & 1;
    const float* w = l == 0 ? w0 : l == 1 ? w1 : w2;
    const float* a = v == 0 ? (l == 0 ? as0 : l == 1 ? as1 : as2)
                            : (l == 0 ? ad0 : l == 1 ? ad1 : ad2);
    ushort_t* o = l == 0 ? ws0 : l == 1 ? ws1 : ws2;
    int K = l == 0 ? F_IN : DM;
    __shared__ float av[HID];
    int t = threadIdx.x;
    if (t < HID) av[t] = a[h * HID + t];
    __syncthreads();
    for (int k = t; k < K; k += 256) {
        const float* wr = w + (size_t)k * DM + h * HID;
        float s = 0.f;
#pragma unroll 8
        for (int c = 0; c < HID; ++c) s += wr[c] * av[c];
        o[(h * 2 + v) * K + k] = f2b(s);
    }
}

// ---------- MFMA GEMM: 3-stage glds pipeline, counted vmcnt (T4) ----------
// C[M,512](bf16) = A[M,K] @ W; scores ssrc/sdst = A @ ws (2 extra cols via MFMA).
// (T5 setprio tested r11: null on this 1-phase-per-K-step structure, reverted.)
__global__ __launch_bounds__(256) void k_mgemm(const ushort_t* __restrict__ A,
                                               const ushort_t* __restrict__ Bh,
                                               const ushort_t* __restrict__ ws,
                                               ushort_t* __restrict__ C,
                                               float* __restrict__ ssrc,
                                               float* __restrict__ sdst,
                                               int M, int K) {
    __shared__ __align__(16) ushort_t Ash[3][128 * 32];
    __shared__ __align__(16) ushort_t Bsh[3][128 * 32];
    __shared__ __align__(16) ushort_t wsh[2 * 512];
    // ---- XCD-grouping block index map ----
    int bid = blockIdx.x;
    int head, yb;
    if (bid < NCHUNK * 32) {
        int chunk = bid >> 5, pos = bid & 31;
        yb = chunk * 8 + (pos & 7);
        head = pos >> 3;
    } else {
        int rem = bid - NCHUNK * 32;
        head = rem & 3;
        yb = NCHUNK * 8 + (rem >> 2);
    }
    int m0 = yb * 128, n0 = head * 128;
    int tid = threadIdx.x;
    int lane = tid & 63, wave = tid >> 6;
    int wm = (wave >> 1) * 64, wn = (wave & 1) * 64;
    floatx4 acc[4][4] = {};
    floatx4 sacc[4] = {};                             // score accum: col0=ps, col1=pd
    for (int i = tid; i < 2 * K; i += 256)
        wsh[i] = ws[(size_t)head * 2 * K + i];
    // ---- staging geometry: wave w fills rows [w*16,w*16+16) and +64, 1KB/issue
    int lrow = lane >> 2, lchunk = lane & 3;          // row-within-16, 16B chunk
    int fs = (lrow & 3) ^ ((lrow >> 2) & 3);          // same f(row) the reads use
    int schunk = lchunk ^ fs;                         // pre-swizzled global chunk
    int ar0 = wave * 16 + lrow;
    int ar1 = ar0 + 64;
    int gr0 = m0 + ar0; if (gr0 >= M) gr0 = M - 1;
    int gr1 = m0 + ar1; if (gr1 >= M) gr1 = M - 1;
    const ushort_t* gA0 = A + (size_t)gr0 * K + schunk * 8;
    const ushort_t* gA1 = A + (size_t)gr1 * K + schunk * 8;
    const ushort_t* gB0 = Bh + (size_t)(n0 + ar0) * K + schunk * 8;
    const ushort_t* gB1 = Bh + (size_t)(n0 + ar1) * K + schunk * 8;
    int rF = lane & 15, q = lane >> 4;
    int swz = ((q ^ (rF & 3) ^ ((rF >> 2) & 3))) * 8; // read-side chunk pos
    ushort_t* As0 = &Ash[0][0]; ushort_t* As1 = &Ash[1][0]; ushort_t* As2 = &Ash[2][0];
    ushort_t* Bs0 = &Bsh[0][0]; ushort_t* Bs1 = &Bsh[1][0]; ushort_t* Bs2 = &Bsh[2][0];
    auto STAGE = [&](ushort_t* Ab, ushort_t* Bb, int koff) {
        glds16(gA0 + koff, Ab + (wave * 16) * 32);
        glds16(gA1 + koff, Ab + (wave * 16 + 64) * 32);
        glds16(gB0 + koff, Bb + (wave * 16) * 32);
        glds16(gB1 + koff, Bb + (wave * 16 + 64) * 32);
    };
    __syncthreads();                      // wsh visible; drains ws loads (vmcnt=0 here)
    STAGE(As0, Bs0, 0);                   // prologue: 2 tiles in flight
    if (K > 32) STAGE(As1, Bs1, 32);
    for (int k0 = 0; k0 < K; k0 += 32) {
        if (k0 + 32 < K) asm volatile("s_waitcnt vmcnt(4)" ::: "memory");
        else             asm volatile("s_waitcnt vmcnt(0)" ::: "memory");
        __builtin_amdgcn_s_barrier();     // all waves' STAGE(t) complete
        __builtin_amdgcn_sched_barrier(0);// pin ds_reads/STAGE below the barrier
        if (k0 + 64 < K) STAGE(As2, Bs2, k0 + 64);   // dist-2 prefetch
        short8 sf = *(const short8*)&wsh[(rF & 1) * K + q * 8 + k0];
        short8 af[4], bf[4];
#pragma unroll
        for (int i = 0; i < 4; ++i)
            af[i] = *(const short8*)&As0[(wm + i * 16 + rF) * 32 + swz];
#pragma unroll
        for (int j = 0; j < 4; ++j)
            bf[j] = *(const short8*)&Bs0[(wn + j * 16 + rF) * 32 + swz];
#pragma unroll
        for (int i = 0; i < 4; ++i) {
            sacc[i] = __builtin_amdgcn_mfma_f32_16x16x32_bf16(af[i], sf, sacc[i], 0, 0, 0);
#pragma unroll
            for (int j = 0; j < 4; ++j)
                acc[i][j] = __builtin_amdgcn_mfma_f32_16x16x32_bf16(af[i], bf[j], acc[i][j], 0, 0, 0);
        }
        ushort_t* tA = As0; As0 = As1; As1 = As2; As2 = tA;
        ushort_t* tB = Bs0; Bs0 = Bs1; Bs1 = Bs2; Bs2 = tB;
    }
    // C/D layout: col=lane&15, row=(lane>>4)*4+reg   [m89-verified]
    int cr = (lane >> 4) * 4, cc = lane & 15;
#pragma unroll
    for (int i = 0; i < 4; ++i) {
#pragma unroll
        for (int r = 0; r < 4; ++r) {
            int gr = m0 + wm + i * 16 + cr + r;
            if (gr < M) {
#pragma unroll
                for (int j = 0; j < 4; ++j)
                    C[(size_t)gr * DM + n0 + wn + j * 16 + cc] = f2b(acc[i][j][r]);
                if (cc == 0) ssrc[gr * 4 + head] = sacc[i][r];
                else if (cc == 1) sdst[gr * 4 + head] = sacc[i][r];
            }
        }
    }
}

// ---------- BN apply + ReLU, elementwise bf16->bf16 ----------
__global__ __launch_bounds__(256) void k_bnapply(const ushort_t* __restrict__ X,
                                                 const float* __restrict__ stat,
                                                 const float* __restrict__ gam,
                                                 const float* __restrict__ bet,
                                                 ushort_t* __restrict__ Y) {
    __shared__ float sc[512], sh[512];
    int t = threadIdx.x;
    for (int f = t; f < 512; f += 256) {
        float mu = stat[f] * (1.f / (float)N_NODES);
        float var = fmaxf(stat[512 + f] * (1.f / (float)N_NODES) - mu * mu, 0.f);
        float rs = rsqrtf(var + BN_EPS);
        float s = gam[f] * rs;
        sc[f] = s;
        sh[f] = bet[f] - mu * s;
    }
    __syncthreads();
    int c8 = (t & 63) * 8;                       // 8 features per thread
    const float* scp = sc + c8;
    const float* shp = sh + c8;
    for (int n = blockIdx.x * 4 + (t >> 6); n < N_NODES; n += gridDim.x * 4) {
        uint4 v = *(const uint4*)&X[(size_t)n * DM + c8];
        float fv[8]; unpack8(v, fv);
        uint4 ov; unsigned* po = (unsigned*)&ov;
#pragma unroll
        for (int j = 0; j < 4; ++j) {
            unsigned lo = f2b(fmaxf(fv[2 * j] * scp[2 * j] + shp[2 * j], 0.f));
            unsigned hi = f2b(fmaxf(fv[2 * j + 1] * scp[2 * j + 1] + shp[2 * j + 1], 0.f));
            po[j] = lo | (hi << 16);
        }
        *(uint4*)&Y[(size_t)n * DM + c8] = ov;
    }
}

// ---------- CSR build ----------
__global__ void k_degree(const int* __restrict__ ei, int* __restrict__ deg) {
    int e = blockIdx.x * blockDim.x + threadIdx.x;
    if (e >= ET_EDGES) return;
    int d = (e < E_EDGES) ? ei[E_EDGES + e] : (e - E_EDGES);
    atomicAdd(&deg[d], 1);
}

// ---------- 3-phase parallel exclusive scan ----------
__global__ __launch_bounds__(1024) void k_scanA(const int* __restrict__ deg,
                                                int* __restrict__ bsum) {
    __shared__ int wsum[16];
    int t = threadIdx.x, lane = t & 63, wv = t >> 6;
    int i = blockIdx.x * 1024 + t;
    int v = (i < N_NODES) ? deg[i] : 0;
#pragma unroll
    for (int off = 32; off > 0; off >>= 1) v += __shfl_down(v, off);
    if (lane == 0) wsum[wv] = v;
    __syncthreads();
    if (t == 0) {
        int s = 0;
#pragma unroll
        for (int w = 0; w < 16; ++w) s += wsum[w];
        bsum[blockIdx.x] = s;
    }
}

__global__ __launch_bounds__(64) void k_scanB(const int* __restrict__ bsum,
                                              int* __restrict__ bpre,
                                              int* __restrict__ offs) {
    int l = threadIdx.x;
    int v = (l < NBLK) ? bsum[l] : 0;
    int x = v;
#pragma unroll
    for (int off = 1; off < 64; off <<= 1) {
        int y = __shfl_up(x, off);
        if (l >= off) x += y;
    }
    if (l < NBLK) bpre[l] = x - v;       // exclusive block prefix
    if (l == NBLK - 1) offs[N_NODES] = x;
}

__global__ __launch_bounds__(1024) void k_scanC(const int* __restrict__ deg,
                                                const int* __restrict__ bpre,
                                                int* __restrict__ offs,
                                                int* __restrict__ cursor) {
    __shared__ int wsum[16];
    int t = threadIdx.x, lane = t & 63, wv = t >> 6;
    int i = blockIdx.x * 1024 + t;
    int v = (i < N_NODES) ? deg[i] : 0;
    int x = v;
#pragma unroll
    for (int off = 1; off < 64; off <<= 1) {
        int y = __shfl_up(x, off);
        if (lane >= off) x += y;
    }
    if (lane == 63) wsum[wv] = x;
    __syncthreads();
    int wpre = 0;
#pragma unroll
    for (int w = 0; w < 16; ++w) wpre += (w < wv) ? wsum[w] : 0;
    int incl = wpre + x;
    if (i < N_NODES) {
        int o = bpre[blockIdx.x] + incl - v;
        offs[i] = o; cursor[i] = o;
    }
}

__global__ void k_scatter(const int* __restrict__ ei, int* __restrict__ cursor,
                          int* __restrict__ csr_src) {
    int e = blockIdx.x * blockDim.x + threadIdx.x;
    if (e >= ET_EDGES) return;
    int sv, d;
    if (e < E_EDGES) { sv = ei[e]; d = ei[E_EDGES + e]; } else { sv = d = e - E_EDGES; }
    int pos = atomicAdd(&cursor[d], 1);
    csr_src[pos] = sv;
}

__global__ void k_gbounds(const int* __restrict__ batch, int* __restrict__ gstart) {
    int i = blockIdx.x * blockDim.x + threadIdx.x;
    if (i >= N_NODES) return;
    int b = batch[i];
    int p = (i == 0) ? -1 : batch[i - 1];
    for (int g = p + 1; g <= b; ++g) gstart[g] = i;
    if (i == N_NODES - 1)
        for (int g = b + 1; g <= G_GRAPHS; ++g) gstart[g] = N_NODES;
}

// ---------- GAT softmax + aggregate + fused BN stats (r10 best) ----------
// 8 waves x 4 nodes; deg<=16 fast path: tree-softmax (one ssrc load + one exp
// per edge) + 4-edge pipelined gather with alpha/src via __shfl (register-only).
__global__ __launch_bounds__(512) void k_aggstats(const ushort_t* __restrict__ H,
                                                  const float* __restrict__ ssrc,
                                                  const float* __restrict__ sdst,
                                                  const int* __restrict__ offs,
                                                  const int* __restrict__ csr_src,
                                                  const float* __restrict__ bias,
                                                  ushort_t* __restrict__ out,
                                                  float* __restrict__ stat) {
    __shared__ float sS[8][512], sQ[8][512];
    int tid = threadIdx.x;
    int wave = tid >> 6, lane = tid & 63;
    int hl = lane >> 4, li = lane & 15;       // head group, index within group
    int gbase = hl << 4;                       // first lane of this head group
    const float* bp = bias + lane * 8;
    float4 b0 = *(const float4*)bp;
    float4 b1 = *(const float4*)(bp + 4);
    float sa[8] = { 0.f }, qa[8] = { 0.f };
    int nbase = blockIdx.x * AGG_NPB + wave * 4;
    for (int ni = 0; ni < 4; ++ni) {
        int n = nbase + ni;
        if (n < N_NODES) {
            int beg = offs[n], end = offs[n + 1];
            int deg = end - beg;
            float sdh = sdst[n * 4 + hl];
            float acc[8] = { 0.f, 0.f, 0.f, 0.f, 0.f, 0.f, 0.f, 0.f };
            if (deg <= 16) {
                // ---- pass 1: one edge per group lane, tree softmax ----
                int sv_li = csr_src[beg + (li < deg ? li : 0)];
                float sc = -1e30f;
                if (li < deg) {
                    float t = ssrc[sv_li * 4 + hl] + sdh;
                    sc = t > 0.f ? t : NEG_SLOPE * t;
                }
                float m = sc;
#pragma unroll
                for (int mk = 1; mk < 16; mk <<= 1) m = fmaxf(m, __shfl_xor(m, mk));
                float ex = (li < deg) ? __expf(sc - m) : 0.f;
                float s = ex;
#pragma unroll
                for (int mk = 1; mk < 16; mk <<= 1) s += __shfl_xor(s, mk);
                float alf = ex / s;            // lane li holds alpha of edge li
                // ---- pass 2: 4-edge pipelined gather, alpha/src via shfl ----
                int e = beg;
                for (; e + 4 <= end; e += 4) {
                    int i0 = e - beg;
                    int sv0 = __shfl(sv_li, gbase + i0);
                    int sv1 = __shfl(sv_li, gbase + i0 + 1);
                    int sv2 = __shfl(sv_li, gbase + i0 + 2);
                    int sv3 = __shfl(sv_li, gbase + i0 + 3);
                    uint4 h0 = *(const uint4*)&H[(size_t)sv0 * DM + lane * 8];
                    uint4 h1 = *(const uint4*)&H[(size_t)sv1 * DM + lane * 8];
                    uint4 h2 = *(const uint4*)&H[(size_t)sv2 * DM + lane * 8];
                    uint4 h3 = *(const uint4*)&H[(size_t)sv3 * DM + lane * 8];
                    float a0 = __shfl(alf, gbase + i0);
                    float a1 = __shfl(alf, gbase + i0 + 1);
                    float a2 = __shfl(alf, gbase + i0 + 2);
                    float a3 = __shfl(alf, gbase + i0 + 3);
                    float f0[8], f1[8], f2[8], f3[8];
                    unpack8(h0, f0); unpack8(h1, f1); unpack8(h2, f2); unpack8(h3, f3);
#pragma unroll
                    for (int j = 0; j < 8; ++j)
                        acc[j] += a0 * f0[j] + a1 * f1[j] + a2 * f2[j] + a3 * f3[j];
                }
                for (; e < end; ++e) {
                    int idx = e - beg;
                    int sv = __shfl(sv_li, gbase + idx);
                    float al = __shfl(alf, gbase + idx);
                    uint4 hv = *(const uint4*)&H[(size_t)sv * DM + lane * 8];
                    float f[8]; unpack8(hv, f);
#pragma unroll
                    for (int j = 0; j < 8; ++j) acc[j] += al * f[j];
                }
            } else {
                // ---- rare deg>16 fallback: online softmax + 4-edge gather ----
                float m = -1e30f, s = 0.f;
                for (int e = beg + li; e < end; e += 16) {
                    float sc = ssrc[csr_src[e] * 4 + hl] + sdh;
                    sc = sc > 0.f ? sc : NEG_SLOPE * sc;
                    if (sc > m) { s = s * __expf(m - sc) + 1.f; m = sc; }
                    else s += __expf(sc - m);
                }
#pragma unroll
                for (int mk = 1; mk < 16; mk <<= 1) {
                    float om = __shfl_xor(m, mk), os = __shfl_xor(s, mk);
                    float mn = fmaxf(m, om);
                    s = s * __expf(m - mn) + os * __expf(om - mn);
                    m = mn;
                }
                float mh = m, inv = 1.f / s;
                int e = beg;
                for (; e + 4 <= end; e += 4) {
                    int sv0 = csr_src[e], sv1 = csr_src[e + 1];
                    int sv2 = csr_src[e + 2], sv3 = csr_src[e + 3];
                    float s0 = ssrc[sv0 * 4 + hl], s1 = ssrc[sv1 * 4 + hl];
                    float s2 = ssrc[sv2 * 4 + hl], s3 = ssrc[sv3 * 4 + hl];
                    uint4 h0 = *(const uint4*)&H[(size_t)sv0 * DM + lane * 8];
                    uint4 h1 = *(const uint4*)&H[(size_t)sv1 * DM + lane * 8];
                    uint4 h2 = *(const uint4*)&H[(size_t)sv2 * DM + lane * 8];
                    uint4 h3 = *(const uint4*)&H[(size_t)sv3 * DM + lane * 8];
                    s0 += sdh; s0 = s0 > 0.f ? s0 : NEG_SLOPE * s0;
                    s1 += sdh; s1 = s1 > 0.f ? s1 : NEG_SLOPE * s1;
                    s2 += sdh; s2 = s2 > 0.f ? s2 : NEG_SLOPE * s2;
                    s3 += sdh; s3 = s3 > 0.f ? s3 : NEG_SLOPE * s3;
                    float a0 = __expf(s0 - mh) * inv, a1 = __expf(s1 - mh) * inv;
                    float a2 = __expf(s2 - mh) * inv, a3 = __expf(s3 - mh) * inv;
                    float f0[8], f1[8], f2[8], f3[8];
                    unpack8(h0, f0); unpack8(h1, f1); unpack8(h2, f2); unpack8(h3, f3);
#pragma unroll
                    for (int j = 0; j < 8; ++j)
                        acc[j] += a0 * f0[j] + a1 * f1[j] + a2 * f2[j] + a3 * f3[j];
                }
                for (; e < end; ++e) {
                    int sv = csr_src[e];
                    float sc = ssrc[sv * 4 + hl] + sdh;
                    sc = sc > 0.f ? sc : NEG_SLOPE * sc;
                    float alpha = __expf(sc - mh) * inv;
                    uint4 hv = *(const uint4*)&H[(size_t)sv * DM + lane * 8];
                    float f[8]; unpack8(hv, f);
#pragma unroll
                    for (int j = 0; j < 8; ++j) acc[j] += alpha * f[j];
                }
            }
            acc[0] += b0.x; acc[1] += b0.y; acc[2] += b0.z; acc[3] += b0.w;
            acc[4] += b1.x; acc[5] += b1.y; acc[6] += b1.z; acc[7] += b1.w;
            uint4 ov; unsigned* po = (unsigned*)&ov;
#pragma unroll
            for (int j = 0; j < 4; ++j)
                po[j] = (unsigned)f2b(acc[2 * j]) | ((unsigned)f2b(acc[2 * j + 1]) << 16);
            *(uint4*)&out[(size_t)n * DM + lane * 8] = ov;
#pragma unroll
            for (int j = 0; j < 8; ++j) {       // BN stats (f32, pre-rounding)
                sa[j] += acc[j];
                qa[j] += acc[j] * acc[j];
            }
        }
    }
#pragma unroll
    for (int j = 0; j < 8; ++j) {
        sS[wave][lane * 8 + j] = sa[j];
        sQ[wave][lane * 8 + j] = qa[j];
    }
    __syncthreads();
    {
        int f = tid & 511;
        if (tid < 512) {
            float a = 0.f, b = 0.f;
#pragma unroll
            for (int w = 0; w < 8; ++w) { a += sS[w][f]; b += sQ[w][f]; }
            atomicAdd(&stat[f], a);
            atomicAdd(&stat[512 + f], b);
        }
    }
}

// ---------- fused graph pooling (BN+ReLU) + MLP head: one block per graph ----
__global__ __launch_bounds__(256) void k_poolmlp(const ushort_t* __restrict__ X,
                                                 const int* __restrict__ gstart,
                                                 const float* __restrict__ stat,
                                                 const float* __restrict__ gam,
                                                 const float* __restrict__ bet,
                                                 const float* __restrict__ c1w,
                                                 const float* __restrict__ c1b,
                                                 const float* __restrict__ c2w,
                                                 const float* __restrict__ c2b,
                                                 const float* __restrict__ c3w,
                                                 const float* __restrict__ c3b,
                                                 float* __restrict__ out) {
    __shared__ float row[1024];    // [0,512)=mean, [512,1024)=max
    __shared__ float part[128];
    __shared__ float h1[128];
    __shared__ float h2[64];
    int g = blockIdx.x, t = threadIdx.x;
    int beg = gstart[g], end = gstart[g + 1];
    // ---- pool phase: 2 feats/thread, BN+ReLU on the fly ----
    int f0 = t * 2;
    float mu0 = stat[f0] * (1.f / (float)N_NODES);
    float va0 = fmaxf(stat[512 + f0] * (1.f / (float)N_NODES) - mu0 * mu0, 0.f);
    float sc0 = gam[f0] * rsqrtf(va0 + BN_EPS);
    float sh0 = bet[f0] - mu0 * sc0;
    float mu1 = stat[f0 + 1] * (1.f / (float)N_NODES);
    float va1 = fmaxf(stat[512 + f0 + 1] * (1.f / (float)N_NODES) - mu1 * mu1, 0.f);
    float sc1 = gam[f0 + 1] * rsqrtf(va1 + BN_EPS);
    float sh1 = bet[f0 + 1] - mu1 * sc1;
    float s0 = 0.f, s1 = 0.f, m0 = -1e30f, m1 = -1e30f;
    for (int nn = beg; nn < end; ++nn) {
        unsigned v = *(const unsigned*)&X[(size_t)nn * DM + f0];
        float x0 = fmaxf(b2f(v & 0xffffu) * sc0 + sh0, 0.f);
        float x1 = fmaxf(b2f(v >> 16) * sc1 + sh1, 0.f);
        s0 += x0; s1 += x1;
        m0 = fmaxf(m0, x0); m1 = fmaxf(m1, x1);
    }
    float cnt = (float)(end - beg);
    float inv = cnt > 0.f ? 1.f / cnt : 0.f;
    row[f0] = s0 * inv;             row[f0 + 1] = s1 * inv;
    row[512 + f0] = cnt > 0.f ? m0 : 0.f;
    row[512 + f0 + 1] = cnt > 0.f ? m1 : 0.f;
    __syncthreads();
    // ---- MLP phase: 2-way K-split over the 1024-wide layer ----
    int half = t >> 7, c = t & 127;
    int k0 = half * 512;
    float a1 = 0.f;
#pragma unroll 8
    for (int k = 0; k < 512; ++k) a1 += row[k0 + k] * c1w[(k0 + k) * 128 + c];
    if (half) part[c] = a1;
    __syncthreads();
    if (!half) h1[c] = fmaxf(a1 + part[c] + c1b[c], 0.f);
    __syncthreads();
    if (t < 64) {
        float a2 = c2b[t];
#pragma unroll 8
        for (int k = 0; k < 128; ++k) a2 += h1[k] * c2w[k * 64 + t];
        h2[t] = fmaxf(a2, 0.f);
    }
    __syncthreads();
    if (t < 64) {
        float p = h2[t] * c3w[t];
#pragma unroll
        for (int off = 32; off > 0; off >>= 1) p += __shfl_down(p, off);
        if (t == 0) {
            float z = p + c3b[0];
            out[g] = 1.f / (1.f + __expf(-z));      // float32 output
        }
    }
}

extern "C" void kernel_launch(void* const* d_in, const int* in_sizes, int n_in,
                              void* d_out, int out_size, void* d_ws, size_t ws_size,
                              hipStream_t stream) {
    const float* x = (const float*)d_in[0];
    const int* ei = (const int*)d_in[1];
    const int* batch = (const int*)d_in[2];
    const float* c1w = (const float*)d_in[21];
    const float* c1b = (const float*)d_in[22];
    const float* c2w = (const float*)d_in[23];
    const float* c2b = (const float*)d_in[24];
    const float* c3w = (const float*)d_in[25];
    const float* c3b = (const float*)d_in[26];

    char* p = (char*)d_ws;
    auto carve = [&](size_t bytes) -> char* {
        char* r = p; p += (bytes + 255) & ~(size_t)255; return r;
    };
    ushort_t* buf0   = (ushort_t*)carve((size_t)N_NODES * DM * 2);   // ping-pong activations
    ushort_t* buf1   = (ushort_t*)carve((size_t)N_NODES * DM * 2);   // ping-pong activations
    ushort_t* Xb     = (ushort_t*)carve((size_t)N_NODES * F_IN * 2); // x in bf16
    ushort_t* Wh0    = (ushort_t*)carve((size_t)F_IN * DM * 2);      // W0^T (bf16)
    ushort_t* Wh1    = (ushort_t*)carve((size_t)DM * DM * 2);        // W1^T (bf16)
    ushort_t* Wh2    = (ushort_t*)carve((size_t)DM * DM * 2);        // W2^T (bf16)
    ushort_t* ws0    = (ushort_t*)carve((size_t)8 * F_IN * 2);       // W0@a vectors (bf16)
    ushort_t* ws1    = (ushort_t*)carve((size_t)8 * DM * 2);
    ushort_t* ws2    = (ushort_t*)carve((size_t)8 * DM * 2);
    float*    ssrc   = (float*)carve((size_t)N_NODES * 4 * 4);
    float*    sdst   = (float*)carve((size_t)N_NODES * 4 * 4);
    int*      deg    = (int*)carve((size_t)N_NODES * 4);
    int*      offs   = (int*)carve((size_t)(N_NODES + 1) * 4);
    int*      cursor = (int*)carve((size_t)N_NODES * 4);
    int*      csrsrc = (int*)carve((size_t)ET_EDGES * 4);
    float*    bnstat = (float*)carve(3 * 1024 * 4);                  // 3 layers' stats
    int*      gstart = (int*)carve((size_t)(G_GRAPHS + 1) * 4);
    int*      bsum   = (int*)carve(64 * 4);
    int*      bpre   = (int*)carve(64 * 4);

    // --- CSR by dst (self-loops appended) + graph bounds + all dtype prep ---
    hipMemsetAsync(deg, 0, (size_t)N_NODES * 4, stream);
    hipMemsetAsync(bnstat, 0, 3 * 1024 * 4, stream);
    k_degree<<<(ET_EDGES + 255) / 256, 256, 0, stream>>>(ei, deg);
    k_scanA<<<NBLK, 1024, 0, stream>>>(deg, bsum);
    k_scanB<<<1, 64, 0, stream>>>(bsum, bpre, offs);
    k_scanC<<<NBLK, 1024, 0, stream>>>(deg, bpre, offs, cursor);
    k_scatter<<<(ET_EDGES + 255) / 256, 256, 0, stream>>>(ei, cursor, csrsrc);
    k_gbounds<<<(N_NODES + 255) / 256, 256, 0, stream>>>(batch, gstart);
    {
        int total = XN + W0N + 2 * W1N;
        k_prep<<<(total + 255) / 256, 256, 0, stream>>>(
            x, (const float*)d_in[3], (const float*)d_in[9], (const float*)d_in[15],
            Xb, Wh0, Wh1, Wh2);
    }
    k_wsprep<<<24, 256, 0, stream>>>(
        (const float*)d_in[3], (const float*)d_in[4], (const float*)d_in[5],
        (const float*)d_in[9], (const float*)d_in[10], (const float*)d_in[11],
        (const float*)d_in[15], (const float*)d_in[16], (const float*)d_in[17],
        ws0, ws1, ws2);

    // Buffer schedule (ping-pong, no extra workspace):
    //  l0: in=Xb,   h=buf1, agg=buf0, An0->buf1
    //  l1: in=buf1, h=buf0, agg=buf1, An1->buf0
    //  l2: in=buf0, h=buf1, agg=buf0; poolmlp reads buf0 (pre-BN) + stat2
    const ushort_t* Whs[3] = { Wh0, Wh1, Wh2 };
    const ushort_t* wss[3] = { ws0, ws1, ws2 };
    const float* pgam = nullptr;
    const float* pbet = nullptr;
    const ushort_t* in = Xb;
    for (int l = 0; l < 3; ++l) {
        int K = (l == 0) ? F_IN : DM;
        const float* bia = (const float*)d_in[6 + 6 * l];
        const float* gam = (const float*)d_in[7 + 6 * l];
        const float* bet = (const float*)d_in[8 + 6 * l];
        ushort_t* h   = (l % 2 == 0) ? buf1 : buf0;
        ushort_t* agg = (l % 2 == 0) ? buf0 : buf1;

        k_mgemm<<<4 * YBLK, 256, 0, stream>>>(
            in, Whs[l], wss[l], h, ssrc, sdst, N_NODES, K);
        k_aggstats<<<(N_NODES + AGG_NPB - 1) / AGG_NPB, 512, 0, stream>>>(
            h, ssrc, sdst, offs, csrsrc, bia, agg, bnstat + l * 1024);
        if (l < 2)   // normalized input for next layer's GEMM, over dead h-buffer
            k_bnapply<<<2048, 256, 0, stream>>>(agg, bnstat + l * 1024, gam, bet, h);
        in = h;
        pgam = gam; pbet = bet;
    }
    k_poolmlp<<<G_GRAPHS, 256, 0, stream>>>(buf0, gstart, bnstat + 2 * 1024,
                                            pgam, pbet,
                                            c1w, c1b, c2w, c2b, c3w, c3b,
                                            (float*)d_out);
}